// Round 8
// baseline (168.329 us; speedup 1.0000x reference)
//
#include <hip/hip_runtime.h>

// XConv bf16-MFMA pipeline. N=16, P=1024, K=16, D=3, Cf=64, Fin=64,
// Ccat=128, DM=4, Cout=128. NPTS=16384 points, 262144 rows.
//
// MFMA conventions (mfma_f32_16x16x32_bf16, m89-verified):
//  A-frag: lane&15 = M-row, k = (lane>>4)*8 + [0..7]  ([M][K] row-major)
//  B-frag: lane&15 = N-col, k = (lane>>4)*8 + [0..7]  ([N][K] row-major)
//  D:      col(N) = lane&15, row(M) = (lane>>4)*4 + reg

#define NPTS 16384

typedef short  s16x8 __attribute__((ext_vector_type(8)));
typedef float  f32x4 __attribute__((ext_vector_type(4)));

__device__ inline unsigned short f2b(float f) {
    unsigned u = __builtin_bit_cast(unsigned, f);
    unsigned r = u + 0x7FFF + ((u >> 16) & 1);
    return (unsigned short)(r >> 16);
}
__device__ inline float b2f(unsigned short b) {
    return __builtin_bit_cast(float, (unsigned)b << 16);
}

#define MFMA(a,b,c) __builtin_amdgcn_mfma_f32_16x16x32_bf16((a),(b),(c),0,0,0)

// ---------------- kW: weight prep (+ zero BN accumulators in spare range) ----------------
__global__ __launch_bounds__(256) void kW_cvt(
    const float* __restrict__ Wxc, const float* __restrict__ Wx1,
    const float* __restrict__ Wx2, const float* __restrict__ Wf2,
    const float* __restrict__ Wpw, const float* __restrict__ Wf1,
    const float* __restrict__ bf1, const float* __restrict__ Wdw,
    unsigned short* __restrict__ Wb, float* __restrict__ W1p,
    unsigned short* __restrict__ Wtb, float* __restrict__ acc)
{
    unsigned short* Wxcb = Wb;            // [256][64] (K 48->64 zero-pad)
    unsigned short* Wx1b = Wxcb + 16384;  // [256][256]
    unsigned short* Wx2b = Wx1b + 65536;  // [256][256]
    unsigned short* Wf2b = Wx2b + 65536;  // [64][64]
    unsigned short* Wpwb = Wf2b + 4096;   // [128][512]
    int idx = blockIdx.x * 256 + threadIdx.x;
    if (idx < 16384) { int o = idx >> 6, j = idx & 63;
        Wxcb[idx] = (j < 48) ? f2b(Wxc[o*48 + j]) : 0; return; }
    idx -= 16384;
    if (idx < 65536) { Wx1b[idx] = f2b(Wx1[idx]); return; }
    idx -= 65536;
    if (idx < 65536) { Wx2b[idx] = f2b(Wx2[idx]); return; }
    idx -= 65536;
    if (idx < 4096)  { Wf2b[idx] = f2b(Wf2[idx]); return; }
    idx -= 4096;
    if (idx < 65536) { Wpwb[idx] = f2b(Wpw[idx]); return; }
    idx -= 65536;
    if (idx < 256)   { int f = idx >> 2, j = idx & 3;
        W1p[idx] = (j < 3) ? Wf1[f*3 + j] : bf1[f]; return; }
    idx -= 256;
    if (idx < 8192)  { int m = idx >> 11, rem = idx & 2047;   // Wtb[m][c][k]
        int c = rem >> 4, k = rem & 15;
        Wtb[idx] = f2b(Wdw[(size_t)(c*4 + m)*16 + k]); return; }
    idx -= 8192;
    if (idx < 256)   { acc[idx] = 0.f; return; }              // accS|accS2
}

// ---------------- kA: X-chain as 3 chained MFMA GEMMs ----------------
#define SA 72
#define SX 264
__global__ __launch_bounds__(256) void kA_mfma(
    const float* __restrict__ rep, const float* __restrict__ pts,
    const unsigned short* __restrict__ Wxcb, const float* __restrict__ bxc,
    const unsigned short* __restrict__ Wx1b, const float* __restrict__ bx1,
    const unsigned short* __restrict__ Wx2b, const float* __restrict__ bx2,
    unsigned short* __restrict__ X3b)
{
    __shared__ __align__(16) unsigned short pA[16*SA];
    __shared__ __align__(16) unsigned short X1s[16*SX];
    __shared__ __align__(16) unsigned short X2s[16*SX];
    const int tid = threadIdx.x;
    const int w = tid >> 6, lane = tid & 63, cl = lane & 15, lg = lane >> 4;
    const int base = blockIdx.x * 16;

    for (int idx = tid; idx < 1024; idx += 256) {
        int pt = idx >> 6, j = idx & 63;
        float v = 0.f;
        if (j < 48) { int d = j >> 4, kk = j & 15;
            v = pts[(size_t)((base+pt)*16 + kk)*3 + d] - rep[(base+pt)*3 + d]; }
        pA[pt*SA + j] = f2b(v);
    }
    __syncthreads();

    f32x4 z = {0.f,0.f,0.f,0.f};
    {   // ph1: X1 = relu(ptsl @ Wxc^T + b), K=64
        f32x4 acc[4] = {z,z,z,z};
        #pragma unroll
        for (int ks = 0; ks < 2; ++ks) {
            s16x8 a = *(const s16x8*)&pA[cl*SA + ks*32 + lg*8];
            #pragma unroll
            for (int ct = 0; ct < 4; ++ct) {
                int o = w*64 + ct*16 + cl;
                s16x8 b = *(const s16x8*)&Wxcb[o*64 + ks*32 + lg*8];
                acc[ct] = MFMA(a, b, acc[ct]);
            }
        }
        #pragma unroll
        for (int ct = 0; ct < 4; ++ct) {
            int o = w*64 + ct*16 + cl;
            float bias = bxc[o];
            #pragma unroll
            for (int r = 0; r < 4; ++r)
                X1s[(lg*4 + r)*SX + o] = f2b(fmaxf(acc[ct][r] + bias, 0.f));
        }
    }
    __syncthreads();

    {   // ph2: X2 = relu(X1 @ Wx1^T + b), K=256
        f32x4 acc[4] = {z,z,z,z};
        #pragma unroll
        for (int ks = 0; ks < 8; ++ks) {
            s16x8 a = *(const s16x8*)&X1s[cl*SX + ks*32 + lg*8];
            #pragma unroll
            for (int ct = 0; ct < 4; ++ct) {
                int o = w*64 + ct*16 + cl;
                s16x8 b = *(const s16x8*)&Wx1b[(size_t)o*256 + ks*32 + lg*8];
                acc[ct] = MFMA(a, b, acc[ct]);
            }
        }
        #pragma unroll
        for (int ct = 0; ct < 4; ++ct) {
            int o = w*64 + ct*16 + cl;
            float bias = bx1[o];
            #pragma unroll
            for (int r = 0; r < 4; ++r)
                X2s[(lg*4 + r)*SX + o] = f2b(fmaxf(acc[ct][r] + bias, 0.f));
        }
    }
    __syncthreads();

    {   // ph3: X3 = X2 @ Wx2^T + b -> global bf16 [p][256]
        f32x4 acc[4] = {z,z,z,z};
        #pragma unroll
        for (int ks = 0; ks < 8; ++ks) {
            s16x8 a = *(const s16x8*)&X2s[cl*SX + ks*32 + lg*8];
            #pragma unroll
            for (int ct = 0; ct < 4; ++ct) {
                int o = w*64 + ct*16 + cl;
                s16x8 b = *(const s16x8*)&Wx2b[(size_t)o*256 + ks*32 + lg*8];
                acc[ct] = MFMA(a, b, acc[ct]);
            }
        }
        #pragma unroll
        for (int ct = 0; ct < 4; ++ct) {
            int o = w*64 + ct*16 + cl;
            float bias = bx2[o];
            #pragma unroll
            for (int r = 0; r < 4; ++r)
                X3b[(size_t)(base + lg*4 + r)*256 + o] = f2b(acc[ct][r] + bias);
        }
    }
}

// ---------------- kB v5: lift + fts_X + depthwise, LDS = fcT only ----------------
// 8 points/block (2048 blocks = 8/CU), 4 waves; wave w handles pts {2w, 2w+1}.
// Depthwise weights read from global Wtb[m][c][k] (bf16) — each wave read is
// 512 contiguous bytes, L2-resident. LDS = 18.4 KB -> 8 blocks/CU.
#define SF 72
__global__ __launch_bounds__(256) void kB_mfma(
    const float* __restrict__ rep, const float* __restrict__ pts,
    const float* __restrict__ fts, const float* __restrict__ W1p,
    const unsigned short* __restrict__ Wf2b, const float* __restrict__ bf2,
    const unsigned short* __restrict__ Wtb, const float* __restrict__ bdw,
    const unsigned short* __restrict__ X3b, unsigned short* __restrict__ dwb)
{
    __shared__ __align__(16) unsigned short fcT[128*SF];  // 18432 B
    const int tid = threadIdx.x;
    const int w = tid >> 6, lane = tid & 63, cl = lane & 15, lg = lane >> 4;
    const int rw = w*16;
    const int frow = lane >> 2, fch = lane & 3;

    f32x4 z = {0.f,0.f,0.f,0.f};
    #pragma unroll
    for (int j = 0; j < 2; ++j) {
        const int pg = blockIdx.x*8 + w*2 + j;

        // fts loads (early, HBM stream)
        float4 fv[4];
        #pragma unroll
        for (int it = 0; it < 4; ++it)
            fv[it] = *(const float4*)&fts[((size_t)pg*16 + frow)*64 + fch*4 + it*16];

        // X A-frag (K 16->32 zero-pad)
        s16x8 xa = {0,0,0,0,0,0,0,0};
        if (lg < 2) xa = *(const s16x8*)&X3b[(size_t)pg*256 + cl*16 + lg*8];

        // FC1 in regs (W1p L1-hot): the f-octets this lane's FC2 B-frag needs
        const int row = pg*16 + cl;
        float x0 = pts[(size_t)row*3+0] - rep[pg*3+0];
        float x1 = pts[(size_t)row*3+1] - rep[pg*3+1];
        float x2 = pts[(size_t)row*3+2] - rep[pg*3+2];
        s16x8 hb[2];
        #pragma unroll
        for (int ks = 0; ks < 2; ++ks) {
            #pragma unroll
            for (int e = 0; e < 8; ++e) {
                int f = ks*32 + lg*8 + e;
                float4 wb4 = *(const float4*)&W1p[f*4];
                float h = fmaxf(wb4.w + wb4.x*x0 + wb4.y*x1 + wb4.z*x2, 0.f);
                hb[ks][e] = (short)f2b(h);
            }
        }

        // stage fts transposed -> fcT[64+c][rw+frow] (wave-private rows)
        #pragma unroll
        for (int it = 0; it < 4; ++it) {
            float vv[4] = {fv[it].x, fv[it].y, fv[it].z, fv[it].w};
            #pragma unroll
            for (int cc = 0; cc < 4; ++cc) {
                int c = fch*4 + it*16 + cc;
                fcT[(64 + c)*SF + rw + frow] = f2b(vv[cc]);
            }
        }

        // FC2 swapped MFMA: D[g][row] -> fcT[g][rw+cl]
        {
            f32x4 acc2[4] = {z,z,z,z};
            #pragma unroll
            for (int ks = 0; ks < 2; ++ks) {
                #pragma unroll
                for (int gt = 0; gt < 4; ++gt) {
                    s16x8 a = *(const s16x8*)&Wf2b[(gt*16 + cl)*64 + ks*32 + lg*8];
                    acc2[gt] = MFMA(a, hb[ks], acc2[gt]);
                }
            }
            #pragma unroll
            for (int gt = 0; gt < 4; ++gt) {
                #pragma unroll
                for (int r = 0; r < 4; ++r) {
                    int g = gt*16 + lg*4 + r;
                    fcT[g*SF + rw + cl] = f2b(fmaxf(acc2[gt][r] + bf2[g], 0.f));
                }
            }
        }

        // fts_X: fx[ct] = X_p @ fcat (wave-private rows, in-order DS pipe)
        f32x4 fx[8];
        #pragma unroll
        for (int ct = 0; ct < 8; ++ct) {
            int c = ct*16 + cl;
            s16x8 b = *(const s16x8*)&fcT[c*SF + rw + (lg & 1)*8];
            fx[ct] = MFMA(xa, b, z);
        }

        // depthwise from global bf16 Wtb (coalesced 512B/instr) -> dwb [p][512]
        #pragma unroll
        for (int ct = 0; ct < 8; ++ct) {
            int c = ct*16 + cl;
            float4 b4 = *(const float4*)&bdw[c*4];
            float om[4];
            #pragma unroll
            for (int m = 0; m < 4; ++m) {
                ushort4 wu = *(const ushort4*)&Wtb[m*2048 + c*16 + lg*4];
                float s = fx[ct][0]*b2f(wu.x) + fx[ct][1]*b2f(wu.y)
                        + fx[ct][2]*b2f(wu.z) + fx[ct][3]*b2f(wu.w);
                s += __shfl_xor(s, 16);
                s += __shfl_xor(s, 32);
                om[m] = s + ((const float*)&b4)[m];
            }
            if (lg == 0) {
                ushort4 pk; pk.x=f2b(om[0]); pk.y=f2b(om[1]); pk.z=f2b(om[2]); pk.w=f2b(om[3]);
                *(ushort4*)&dwb[(size_t)pg*512 + c*4] = pk;
            }
        }
    }
}

// ---------------- kC2: pointwise MFMA GEMM + fused BN partial stats ----------------
__global__ __launch_bounds__(256) void kC_mfma(
    const unsigned short* __restrict__ dwb, const unsigned short* __restrict__ Wpwb,
    const float* __restrict__ bpw, float* __restrict__ y,
    float* __restrict__ accS, float* __restrict__ accS2)
{
    const int tid = threadIdx.x;
    const int w = tid >> 6, lane = tid & 63, cl = lane & 15, lg = lane >> 4;
    const int m0 = blockIdx.x*32 + (w & 1)*16;
    const int nh = w >> 1;
    f32x4 z = {0.f,0.f,0.f,0.f};
    f32x4 acc[4] = {z,z,z,z};
    for (int ks = 0; ks < 16; ++ks) {
        s16x8 a = *(const s16x8*)&dwb[(size_t)(m0 + cl)*512 + ks*32 + lg*8];
        #pragma unroll
        for (int ct = 0; ct < 4; ++ct) {
            int o = nh*64 + ct*16 + cl;
            s16x8 b = *(const s16x8*)&Wpwb[(size_t)o*512 + ks*32 + lg*8];
            acc[ct] = MFMA(a, b, acc[ct]);
        }
    }
    #pragma unroll
    for (int ct = 0; ct < 4; ++ct) {
        int o = nh*64 + ct*16 + cl;
        float bias = bpw[o];
        float s1 = 0.f, s2 = 0.f;
        #pragma unroll
        for (int r = 0; r < 4; ++r) {
            float v = acc[ct][r] + bias;
            y[(size_t)(m0 + lg*4 + r)*128 + o] = v;
            s1 += v; s2 += v*v;
        }
        s1 += __shfl_xor(s1, 16); s2 += __shfl_xor(s2, 16);
        s1 += __shfl_xor(s1, 32); s2 += __shfl_xor(s2, 32);
        if (lg == 0) {
            atomicAdd(accS + o, s1);
            atomicAdd(accS2 + o, s2);
        }
    }
}

// ---------------- kD2 / kE ----------------
__global__ void kD2_fin(
    const float* __restrict__ accS, const float* __restrict__ accS2,
    const float* __restrict__ gamma, const float* __restrict__ beta,
    float* __restrict__ st)
{
    const int c = threadIdx.x;
    float mean = accS[c] * (1.f/NPTS);
    float var  = accS2[c] * (1.f/NPTS) - mean*mean;
    float rstd = rsqrtf(var + 1e-5f);
    float sc = gamma[c] * rstd;
    st[c] = sc;
    st[128 + c] = beta[c] - mean*sc;
}

__global__ __launch_bounds__(256) void kE_final(
    const float* __restrict__ y, const float* __restrict__ st,
    float* __restrict__ out)
{
    const int idx = blockIdx.x*256 + threadIdx.x;
    float4 v = ((const float4*)y)[idx];
    int o0 = (idx & 31) << 2;
    float4 sc = *(const float4*)(st + o0);
    float4 sh = *(const float4*)(st + 128 + o0);
    float4 r;
    r.x = fmaxf(v.x*sc.x + sh.x, 0.f);
    r.y = fmaxf(v.y*sc.y + sh.y, 0.f);
    r.z = fmaxf(v.z*sc.z + sh.z, 0.f);
    r.w = fmaxf(v.w*sc.w + sh.w, 0.f);
    ((float4*)out)[idx] = r;
}

extern "C" void kernel_launch(void* const* d_in, const int* in_sizes, int n_in,
                              void* d_out, int out_size, void* d_ws, size_t ws_size,
                              hipStream_t stream) {
    const float* rep  = (const float*)d_in[0];
    const float* pts  = (const float*)d_in[1];
    const float* fts  = (const float*)d_in[2];
    const float* Wf1  = (const float*)d_in[3];
    const float* bf1  = (const float*)d_in[4];
    const float* Wf2  = (const float*)d_in[5];
    const float* bf2  = (const float*)d_in[6];
    const float* Wxc  = (const float*)d_in[7];
    const float* bxc  = (const float*)d_in[8];
    const float* Wx1  = (const float*)d_in[9];
    const float* bx1  = (const float*)d_in[10];
    const float* Wx2  = (const float*)d_in[11];
    const float* bx2  = (const float*)d_in[12];
    const float* Wdw  = (const float*)d_in[13];
    const float* bdw  = (const float*)d_in[14];
    const float* Wpw  = (const float*)d_in[15];
    const float* bpw  = (const float*)d_in[16];
    const float* gam  = (const float*)d_in[17];
    const float* bet  = (const float*)d_in[18];

    unsigned short* X3b = (unsigned short*)d_ws;                 // 16384*256 bf16
    unsigned short* dwb = X3b + (size_t)NPTS*256;                // 16384*512 bf16
    float* y   = (float*)(dwb + (size_t)NPTS*512);               // 16384*128 f32
    float* st  = y + (size_t)NPTS*128;                           // 256
    float* acc = st + 256;                                       // 256
    unsigned short* Wb = (unsigned short*)(acc + 256);           // 217088 bf16
    unsigned short* Wxcb = Wb;
    unsigned short* Wx1b = Wxcb + 16384;
    unsigned short* Wx2b = Wx1b + 65536;
    unsigned short* Wf2b = Wx2b + 65536;
    unsigned short* Wpwb = Wf2b + 4096;
    float* W1p = (float*)(Wb + 217088);                          // 256 f32
    unsigned short* Wtb = (unsigned short*)(W1p + 256);          // 8192 bf16

    kW_cvt<<<882, 256, 0, stream>>>(Wxc, Wx1, Wx2, Wf2, Wpw, Wf1, bf1, Wdw,
                                    Wb, W1p, Wtb, acc);
    kA_mfma<<<NPTS/16, 256, 0, stream>>>(rep, pts, Wxcb, bxc, Wx1b, bx1, Wx2b, bx2, X3b);
    kB_mfma<<<NPTS/8, 256, 0, stream>>>(rep, pts, fts, W1p, Wf2b, bf2, Wtb, bdw, X3b, dwb);
    kC_mfma<<<NPTS/32, 256, 0, stream>>>(dwb, Wpwb, bpw, y, acc, acc + 128);
    kD2_fin<<<1, 128, 0, stream>>>(acc, acc + 128, gam, bet, st);
    kE_final<<<(NPTS*128/4)/256, 256, 0, stream>>>(y, st, (float*)d_out);
}

// Round 9
// 120.671 us; speedup vs baseline: 1.3949x; 1.3949x over previous
//
#include <hip/hip_runtime.h>

// XConv bf16-MFMA pipeline, fragment-packed weights.
// N=16, P=1024, K=16, D=3, Cf=64, Fin=64, Ccat=128, DM=4, Cout=128.
//
// MFMA conventions (mfma_f32_16x16x32_bf16, m89-verified):
//  A-frag: lane&15 = M-row, k = (lane>>4)*8 + [0..7]  ([M][K] row-major)
//  B-frag: lane&15 = N-col, k = (lane>>4)*8 + [0..7]  ([N][K] row-major)
//  D:      col(N) = lane&15, row(M) = (lane>>4)*4 + reg
//
// Packed weight layout (per [O][K] weight, 16-col tiles, K-steps of 32):
//  Wpk[((ot*(K/32) + ks)*64 + lane)*8 + e] = W[ot*16 + (lane&15)][ks*32 + (lane>>4)*8 + e]
//  -> a wave's B-frag load is 1 contiguous KB (fully coalesced).

#define NPTS 16384

typedef short  s16x8 __attribute__((ext_vector_type(8)));
typedef float  f32x4 __attribute__((ext_vector_type(4)));

__device__ inline unsigned short f2b(float f) {
    unsigned u = __builtin_bit_cast(unsigned, f);
    unsigned r = u + 0x7FFF + ((u >> 16) & 1);
    return (unsigned short)(r >> 16);
}
__device__ inline float b2f(unsigned short b) {
    return __builtin_bit_cast(float, (unsigned)b << 16);
}

#define MFMA(a,b,c) __builtin_amdgcn_mfma_f32_16x16x32_bf16((a),(b),(c),0,0,0)

// ---------------- kW: weight prep (frag-packed) + W1 pack + Wt + acc zero ----------------
__global__ __launch_bounds__(256) void kW_cvt(
    const float* __restrict__ Wxc, const float* __restrict__ Wx1,
    const float* __restrict__ Wx2, const float* __restrict__ Wf2,
    const float* __restrict__ Wpw, const float* __restrict__ Wf1,
    const float* __restrict__ bf1, const float* __restrict__ Wdw,
    unsigned short* __restrict__ Wpk, float* __restrict__ W1p,
    unsigned short* __restrict__ Wtb, float* __restrict__ acc)
{
    unsigned short* Wxcpk = Wpk;             // O=256 K=64   : 16384
    unsigned short* Wx1pk = Wpk + 16384;     // O=256 K=256  : 65536
    unsigned short* Wx2pk = Wpk + 81920;     // O=256 K=256  : 65536
    unsigned short* Wf2pk = Wpk + 147456;    // O=64  K=64   : 4096
    unsigned short* Wpwpk = Wpk + 151552;    // O=128 K=512  : 65536
    int idx = blockIdx.x * 256 + threadIdx.x;
    if (idx < 16384) {            // Wxc [256][48] -> K=64 pad
        int e = idx & 7, ln = (idx >> 3) & 63, ks = (idx >> 9) & 1, ot = idx >> 10;
        int row = ot*16 + (ln & 15), k = ks*32 + (ln >> 4)*8 + e;
        Wxcpk[idx] = (k < 48) ? f2b(Wxc[row*48 + k]) : 0; return; }
    idx -= 16384;
    if (idx < 65536) {            // Wx1 [256][256]
        int e = idx & 7, ln = (idx >> 3) & 63, ks = (idx >> 9) & 7, ot = idx >> 12;
        int row = ot*16 + (ln & 15), k = ks*32 + (ln >> 4)*8 + e;
        Wx1pk[idx] = f2b(Wx1[row*256 + k]); return; }
    idx -= 65536;
    if (idx < 65536) {            // Wx2 [256][256]
        int e = idx & 7, ln = (idx >> 3) & 63, ks = (idx >> 9) & 7, ot = idx >> 12;
        int row = ot*16 + (ln & 15), k = ks*32 + (ln >> 4)*8 + e;
        Wx2pk[idx] = f2b(Wx2[row*256 + k]); return; }
    idx -= 65536;
    if (idx < 4096) {             // Wf2 [64][64]
        int e = idx & 7, ln = (idx >> 3) & 63, ks = (idx >> 9) & 1, ot = idx >> 10;
        int row = ot*16 + (ln & 15), k = ks*32 + (ln >> 4)*8 + e;
        Wf2pk[idx] = f2b(Wf2[row*64 + k]); return; }
    idx -= 4096;
    if (idx < 65536) {            // Wpw [128][512]
        int e = idx & 7, ln = (idx >> 3) & 63, ks = (idx >> 9) & 15, ot = idx >> 13;
        int row = ot*16 + (ln & 15), k = ks*32 + (ln >> 4)*8 + e;
        Wpwpk[idx] = f2b(Wpw[row*512 + k]); return; }
    idx -= 65536;
    if (idx < 256)   { int f = idx >> 2, j = idx & 3;
        W1p[idx] = (j < 3) ? Wf1[f*3 + j] : bf1[f]; return; }
    idx -= 256;
    if (idx < 8192)  { int m = idx >> 11, rem = idx & 2047;   // Wtb[m][c][k]
        int c = rem >> 4, k = rem & 15;
        Wtb[idx] = f2b(Wdw[(size_t)(c*4 + m)*16 + k]); return; }
    idx -= 8192;
    if (idx < 256)   { acc[idx] = 0.f; return; }              // accS|accS2
}

// ---------------- kA v2: X-chain, 32 pts/block, 512 thr, 2 barriers ----------------
// wave w: mw = w&1 (row-tile of 16 pts), nw = w>>1 (col-quarter of 64).
#define SX 264
__global__ __launch_bounds__(512) void kA_mfma(
    const float* __restrict__ rep, const float* __restrict__ pts,
    const unsigned short* __restrict__ Wpk,
    const float* __restrict__ bxc, const float* __restrict__ bx1,
    const float* __restrict__ bx2, unsigned short* __restrict__ X3b)
{
    const unsigned short* Wxcpk = Wpk;
    const unsigned short* Wx1pk = Wpk + 16384;
    const unsigned short* Wx2pk = Wpk + 81920;
    __shared__ __align__(16) unsigned short X1s[32*SX];
    __shared__ __align__(16) unsigned short X2s[32*SX];
    const int tid = threadIdx.x;
    const int w = tid >> 6, lane = tid & 63, cl = lane & 15, lg = lane >> 4;
    const int mw = w & 1, nw = w >> 1;
    const int base = blockIdx.x * 32;
    const int q = base + mw*16 + cl;          // this lane's A-row point
    f32x4 z = {0.f,0.f,0.f,0.f};

    // ---- ph1 A-frag from global (no staging barrier) ----
    float r0 = rep[q*3+0], r1 = rep[q*3+1], r2 = rep[q*3+2];
    s16x8 aa[2];
    #pragma unroll
    for (int ks = 0; ks < 2; ++ks) {
        #pragma unroll
        for (int e = 0; e < 8; ++e) {
            int j = ks*32 + lg*8 + e;
            float v = 0.f;
            if (j < 48) {
                int d = j >> 4, kk = j & 15;
                float rv = (d == 0) ? r0 : ((d == 1) ? r1 : r2);
                v = pts[(size_t)(q*16 + kk)*3 + d] - rv;
            }
            aa[ks][e] = (short)f2b(v);
        }
    }

    {   // ph1: X1 = relu(ptsl @ Wxc^T + b), K=64
        f32x4 acc[4] = {z,z,z,z};
        #pragma unroll
        for (int ks = 0; ks < 2; ++ks) {
            #pragma unroll
            for (int ct = 0; ct < 4; ++ct) {
                int ot = nw*4 + ct;
                s16x8 b = *(const s16x8*)&Wxcpk[((ot*2 + ks)*64 + lane)*8];
                acc[ct] = MFMA(aa[ks], b, acc[ct]);
            }
        }
        #pragma unroll
        for (int ct = 0; ct < 4; ++ct) {
            int o = nw*64 + ct*16 + cl;
            float bias = bxc[o];
            #pragma unroll
            for (int r = 0; r < 4; ++r)
                X1s[(mw*16 + lg*4 + r)*SX + o] = f2b(fmaxf(acc[ct][r] + bias, 0.f));
        }
    }
    __syncthreads();

    {   // ph2: X2 = relu(X1 @ Wx1^T + b), K=256
        f32x4 acc[4] = {z,z,z,z};
        #pragma unroll
        for (int ks = 0; ks < 8; ++ks) {
            s16x8 a = *(const s16x8*)&X1s[(mw*16 + cl)*SX + ks*32 + lg*8];
            #pragma unroll
            for (int ct = 0; ct < 4; ++ct) {
                int ot = nw*4 + ct;
                s16x8 b = *(const s16x8*)&Wx1pk[((ot*8 + ks)*64 + lane)*8];
                acc[ct] = MFMA(a, b, acc[ct]);
            }
        }
        #pragma unroll
        for (int ct = 0; ct < 4; ++ct) {
            int o = nw*64 + ct*16 + cl;
            float bias = bx1[o];
            #pragma unroll
            for (int r = 0; r < 4; ++r)
                X2s[(mw*16 + lg*4 + r)*SX + o] = f2b(fmaxf(acc[ct][r] + bias, 0.f));
        }
    }
    __syncthreads();

    {   // ph3: X3 = X2 @ Wx2^T + b (linear) -> global bf16 [p][256]
        f32x4 acc[4] = {z,z,z,z};
        #pragma unroll
        for (int ks = 0; ks < 8; ++ks) {
            s16x8 a = *(const s16x8*)&X2s[(mw*16 + cl)*SX + ks*32 + lg*8];
            #pragma unroll
            for (int ct = 0; ct < 4; ++ct) {
                int ot = nw*4 + ct;
                s16x8 b = *(const s16x8*)&Wx2pk[((ot*8 + ks)*64 + lane)*8];
                acc[ct] = MFMA(a, b, acc[ct]);
            }
        }
        #pragma unroll
        for (int ct = 0; ct < 4; ++ct) {
            int o = nw*64 + ct*16 + cl;
            float bias = bx2[o];
            #pragma unroll
            for (int r = 0; r < 4; ++r)
                X3b[(size_t)(base + mw*16 + lg*4 + r)*256 + o] = f2b(acc[ct][r] + bias);
        }
    }
}

// ---------------- kB v6: R5 barrier-free structure + packed Wf2 + coalesced Wtb ----------------
// 4 points/block (4096 blocks), 4 waves; wave w owns point p and LDS rows w*16..+15.
#define SF 72
__global__ __launch_bounds__(256) void kB_mfma(
    const float* __restrict__ rep, const float* __restrict__ pts,
    const float* __restrict__ fts, const float* __restrict__ W1p,
    const unsigned short* __restrict__ Wpk, const float* __restrict__ bf2,
    const unsigned short* __restrict__ Wtb, const float* __restrict__ bdw,
    const unsigned short* __restrict__ X3b, unsigned short* __restrict__ dwb)
{
    const unsigned short* Wf2pk = Wpk + 147456;
    __shared__ __align__(16) unsigned short fcT[128*SF];  // 18432 B
    const int tid = threadIdx.x;
    const int w = tid >> 6, lane = tid & 63, cl = lane & 15, lg = lane >> 4;
    const int p = blockIdx.x*4 + w;
    const int rw = w*16;

    // ---- issue global loads early ----
    const int frow = lane >> 2, fch = lane & 3;
    float4 fv[4];
    #pragma unroll
    for (int it = 0; it < 4; ++it)
        fv[it] = *(const float4*)&fts[((size_t)p*16 + frow)*64 + fch*4 + it*16];

    s16x8 xa = {0,0,0,0,0,0,0,0};
    if (lg < 2) xa = *(const s16x8*)&X3b[(size_t)p*256 + cl*16 + lg*8];

    const int row = p*16 + cl;
    float x0 = pts[(size_t)row*3+0] - rep[p*3+0];
    float x1 = pts[(size_t)row*3+1] - rep[p*3+1];
    float x2 = pts[(size_t)row*3+2] - rep[p*3+2];

    // ---- FC1 in regs: the f-octets this lane's FC2 B-frag needs ----
    s16x8 hb[2];
    #pragma unroll
    for (int ks = 0; ks < 2; ++ks) {
        #pragma unroll
        for (int e = 0; e < 8; ++e) {
            int f = ks*32 + lg*8 + e;
            float4 wb4 = *(const float4*)&W1p[f*4];
            float h = fmaxf(wb4.w + wb4.x*x0 + wb4.y*x1 + wb4.z*x2, 0.f);
            hb[ks][e] = (short)f2b(h);
        }
    }

    // ---- stage fts transposed -> fcT[64+c][rw+frow] (wave-private rows) ----
    #pragma unroll
    for (int it = 0; it < 4; ++it) {
        float vv[4] = {fv[it].x, fv[it].y, fv[it].z, fv[it].w};
        #pragma unroll
        for (int cc = 0; cc < 4; ++cc) {
            int c = fch*4 + it*16 + cc;
            fcT[(64 + c)*SF + rw + frow] = f2b(vv[cc]);
        }
    }

    f32x4 z = {0.f,0.f,0.f,0.f};
    // ---- FC2 swapped MFMA: D[g][row_local], A = packed Wf2 (coalesced) ----
    {
        f32x4 acc2[4] = {z,z,z,z};
        #pragma unroll
        for (int ks = 0; ks < 2; ++ks) {
            #pragma unroll
            for (int gt = 0; gt < 4; ++gt) {
                s16x8 a = *(const s16x8*)&Wf2pk[((gt*2 + ks)*64 + lane)*8];
                acc2[gt] = MFMA(a, hb[ks], acc2[gt]);
            }
        }
        #pragma unroll
        for (int gt = 0; gt < 4; ++gt) {
            #pragma unroll
            for (int r = 0; r < 4; ++r) {
                int g = gt*16 + lg*4 + r;
                fcT[g*SF + rw + cl] = f2b(fmaxf(acc2[gt][r] + bf2[g], 0.f));
            }
        }
    }

    // ---- fts_X: fx[ct] = X_p @ fcat (wave-private rows; no barrier) ----
    f32x4 fx[8];
    #pragma unroll
    for (int ct = 0; ct < 8; ++ct) {
        int c = ct*16 + cl;
        s16x8 b = *(const s16x8*)&fcT[c*SF + rw + (lg & 1)*8];
        fx[ct] = MFMA(xa, b, z);
    }

    // ---- depthwise from coalesced bf16 Wtb[m][c][k] -> dwb [p][512] ----
    #pragma unroll
    for (int ct = 0; ct < 8; ++ct) {
        int c = ct*16 + cl;
        float4 b4 = *(const float4*)&bdw[c*4];
        float om[4];
        #pragma unroll
        for (int m = 0; m < 4; ++m) {
            ushort4 wu = *(const ushort4*)&Wtb[m*2048 + c*16 + lg*4];
            float s = fx[ct][0]*b2f(wu.x) + fx[ct][1]*b2f(wu.y)
                    + fx[ct][2]*b2f(wu.z) + fx[ct][3]*b2f(wu.w);
            s += __shfl_xor(s, 16);
            s += __shfl_xor(s, 32);
            om[m] = s + ((const float*)&b4)[m];
        }
        if (lg == 0) {
            ushort4 pk; pk.x=f2b(om[0]); pk.y=f2b(om[1]); pk.z=f2b(om[2]); pk.w=f2b(om[3]);
            *(ushort4*)&dwb[(size_t)p*512 + c*4] = pk;
        }
    }
}

// ---------------- kC: pointwise MFMA GEMM + fused BN partial stats ----------------
__global__ __launch_bounds__(256) void kC_mfma(
    const unsigned short* __restrict__ dwb, const unsigned short* __restrict__ Wpk,
    const float* __restrict__ bpw, float* __restrict__ y,
    float* __restrict__ accS, float* __restrict__ accS2)
{
    const unsigned short* Wpwpk = Wpk + 151552;
    const int tid = threadIdx.x;
    const int w = tid >> 6, lane = tid & 63, cl = lane & 15, lg = lane >> 4;
    const int m0 = blockIdx.x*32 + (w & 1)*16;
    const int nh = w >> 1;
    f32x4 z = {0.f,0.f,0.f,0.f};
    f32x4 acc[4] = {z,z,z,z};
    for (int ks = 0; ks < 16; ++ks) {
        s16x8 a = *(const s16x8*)&dwb[(size_t)(m0 + cl)*512 + ks*32 + lg*8];
        #pragma unroll
        for (int ct = 0; ct < 4; ++ct) {
            int ot = nh*4 + ct;
            s16x8 b = *(const s16x8*)&Wpwpk[((ot*16 + ks)*64 + lane)*8];
            acc[ct] = MFMA(a, b, acc[ct]);
        }
    }
    #pragma unroll
    for (int ct = 0; ct < 4; ++ct) {
        int o = nh*64 + ct*16 + cl;
        float bias = bpw[o];
        float s1 = 0.f, s2 = 0.f;
        #pragma unroll
        for (int r = 0; r < 4; ++r) {
            float v = acc[ct][r] + bias;
            y[(size_t)(m0 + lg*4 + r)*128 + o] = v;
            s1 += v; s2 += v*v;
        }
        s1 += __shfl_xor(s1, 16); s2 += __shfl_xor(s2, 16);
        s1 += __shfl_xor(s1, 32); s2 += __shfl_xor(s2, 32);
        if (lg == 0) {
            atomicAdd(accS + o, s1);
            atomicAdd(accS2 + o, s2);
        }
    }
}

// ---------------- kD2 / kE ----------------
__global__ void kD2_fin(
    const float* __restrict__ accS, const float* __restrict__ accS2,
    const float* __restrict__ gamma, const float* __restrict__ beta,
    float* __restrict__ st)
{
    const int c = threadIdx.x;
    float mean = accS[c] * (1.f/NPTS);
    float var  = accS2[c] * (1.f/NPTS) - mean*mean;
    float rstd = rsqrtf(var + 1e-5f);
    float sc = gamma[c] * rstd;
    st[c] = sc;
    st[128 + c] = beta[c] - mean*sc;
}

__global__ __launch_bounds__(256) void kE_final(
    const float* __restrict__ y, const float* __restrict__ st,
    float* __restrict__ out)
{
    const int idx = blockIdx.x*256 + threadIdx.x;
    float4 v = ((const float4*)y)[idx];
    int o0 = (idx & 31) << 2;
    float4 sc = *(const float4*)(st + o0);
    float4 sh = *(const float4*)(st + 128 + o0);
    float4 r;
    r.x = fmaxf(v.x*sc.x + sh.x, 0.f);
    r.y = fmaxf(v.y*sc.y + sh.y, 0.f);
    r.z = fmaxf(v.z*sc.z + sh.z, 0.f);
    r.w = fmaxf(v.w*sc.w + sh.w, 0.f);
    ((float4*)out)[idx] = r;
}

extern "C" void kernel_launch(void* const* d_in, const int* in_sizes, int n_in,
                              void* d_out, int out_size, void* d_ws, size_t ws_size,
                              hipStream_t stream) {
    const float* rep  = (const float*)d_in[0];
    const float* pts  = (const float*)d_in[1];
    const float* fts  = (const float*)d_in[2];
    const float* Wf1  = (const float*)d_in[3];
    const float* bf1  = (const float*)d_in[4];
    const float* Wf2  = (const float*)d_in[5];
    const float* bf2  = (const float*)d_in[6];
    const float* Wxc  = (const float*)d_in[7];
    const float* bxc  = (const float*)d_in[8];
    const float* Wx1  = (const float*)d_in[9];
    const float* bx1  = (const float*)d_in[10];
    const float* Wx2  = (const float*)d_in[11];
    const float* bx2  = (const float*)d_in[12];
    const float* Wdw  = (const float*)d_in[13];
    const float* bdw  = (const float*)d_in[14];
    const float* Wpw  = (const float*)d_in[15];
    const float* bpw  = (const float*)d_in[16];
    const float* gam  = (const float*)d_in[17];
    const float* bet  = (const float*)d_in[18];

    unsigned short* X3b = (unsigned short*)d_ws;                 // 16384*256 bf16
    unsigned short* dwb = X3b + (size_t)NPTS*256;                // 16384*512 bf16
    float* y   = (float*)(dwb + (size_t)NPTS*512);               // 16384*128 f32
    float* st  = y + (size_t)NPTS*128;                           // 256
    float* acc = st + 256;                                       // 256
    unsigned short* Wpk = (unsigned short*)(acc + 256);          // 217088 bf16
    float* W1p = (float*)(Wpk + 217088);                         // 256 f32
    unsigned short* Wtb = (unsigned short*)(W1p + 256);          // 8192 bf16

    kW_cvt<<<882, 256, 0, stream>>>(Wxc, Wx1, Wx2, Wf2, Wpw, Wf1, bf1, Wdw,
                                    Wpk, W1p, Wtb, acc);
    kA_mfma<<<NPTS/32, 512, 0, stream>>>(rep, pts, Wpk, bxc, bx1, bx2, X3b);
    kB_mfma<<<NPTS/4, 256, 0, stream>>>(rep, pts, fts, W1p, Wpk, bf2, Wtb, bdw, X3b, dwb);
    kC_mfma<<<NPTS/32, 256, 0, stream>>>(dwb, Wpk, bpw, y, acc, acc + 128);
    kD2_fin<<<1, 128, 0, stream>>>(acc, acc + 128, gam, bet, st);
    kE_final<<<(NPTS*128/4)/256, 256, 0, stream>>>(y, st, (float*)d_out);
}

// Round 10
// 116.830 us; speedup vs baseline: 1.4408x; 1.0329x over previous
//
#include <hip/hip_runtime.h>

// XConv bf16-MFMA pipeline, fragment-packed weights + v_cvt_pk_bf16_f32.
// N=16, P=1024, K=16, D=3, Cf=64, Fin=64, Ccat=128, DM=4, Cout=128.
//
// MFMA conventions (mfma_f32_16x16x32_bf16, m89-verified):
//  A-frag: lane&15 = M-row, k = (lane>>4)*8 + [0..7]  ([M][K] row-major)
//  B-frag: lane&15 = N-col, k = (lane>>4)*8 + [0..7]  ([N][K] row-major)
//  D:      col(N) = lane&15, row(M) = (lane>>4)*4 + reg
//
// Packed weight layout (per [O][K] weight, 16-col tiles, K-steps of 32):
//  Wpk[((ot*(K/32) + ks)*64 + lane)*8 + e] = W[ot*16 + (lane&15)][ks*32 + (lane>>4)*8 + e]

#define NPTS 16384

typedef short  s16x8 __attribute__((ext_vector_type(8)));
typedef float  f32x4 __attribute__((ext_vector_type(4)));

__device__ inline unsigned short f2b(float f) {
    unsigned u = __builtin_bit_cast(unsigned, f);
    unsigned r = u + 0x7FFF + ((u >> 16) & 1);
    return (unsigned short)(r >> 16);
}
__device__ inline float b2f(unsigned short b) {
    return __builtin_bit_cast(float, (unsigned)b << 16);
}
// packed RNE f32x2 -> bf16x2 (lo -> [15:0], hi -> [31:16])
__device__ inline unsigned cvtpk(float lo, float hi) {
    unsigned r;
    asm("v_cvt_pk_bf16_f32 %0, %1, %2" : "=v"(r) : "v"(lo), "v"(hi));
    return r;
}

#define MFMA(a,b,c) __builtin_amdgcn_mfma_f32_16x16x32_bf16((a),(b),(c),0,0,0)

// ---------------- kW: weight prep (frag-packed) + W1 pack + Wt + acc zero ----------------
__global__ __launch_bounds__(256) void kW_cvt(
    const float* __restrict__ Wxc, const float* __restrict__ Wx1,
    const float* __restrict__ Wx2, const float* __restrict__ Wf2,
    const float* __restrict__ Wpw, const float* __restrict__ Wf1,
    const float* __restrict__ bf1, const float* __restrict__ Wdw,
    unsigned short* __restrict__ Wpk, float* __restrict__ W1p,
    unsigned short* __restrict__ Wtb, float* __restrict__ acc)
{
    unsigned short* Wxcpk = Wpk;             // O=256 K=64   : 16384
    unsigned short* Wx1pk = Wpk + 16384;     // O=256 K=256  : 65536
    unsigned short* Wx2pk = Wpk + 81920;     // O=256 K=256  : 65536
    unsigned short* Wf2pk = Wpk + 147456;    // O=64  K=64   : 4096
    unsigned short* Wpwpk = Wpk + 151552;    // O=128 K=512  : 65536
    int idx = blockIdx.x * 256 + threadIdx.x;
    if (idx < 16384) {            // Wxc [256][48] -> K=64 pad
        int e = idx & 7, ln = (idx >> 3) & 63, ks = (idx >> 9) & 1, ot = idx >> 10;
        int row = ot*16 + (ln & 15), k = ks*32 + (ln >> 4)*8 + e;
        Wxcpk[idx] = (k < 48) ? f2b(Wxc[row*48 + k]) : 0; return; }
    idx -= 16384;
    if (idx < 65536) {            // Wx1 [256][256]
        int e = idx & 7, ln = (idx >> 3) & 63, ks = (idx >> 9) & 7, ot = idx >> 12;
        int row = ot*16 + (ln & 15), k = ks*32 + (ln >> 4)*8 + e;
        Wx1pk[idx] = f2b(Wx1[row*256 + k]); return; }
    idx -= 65536;
    if (idx < 65536) {            // Wx2 [256][256]
        int e = idx & 7, ln = (idx >> 3) & 63, ks = (idx >> 9) & 7, ot = idx >> 12;
        int row = ot*16 + (ln & 15), k = ks*32 + (ln >> 4)*8 + e;
        Wx2pk[idx] = f2b(Wx2[row*256 + k]); return; }
    idx -= 65536;
    if (idx < 4096) {             // Wf2 [64][64]
        int e = idx & 7, ln = (idx >> 3) & 63, ks = (idx >> 9) & 1, ot = idx >> 10;
        int row = ot*16 + (ln & 15), k = ks*32 + (ln >> 4)*8 + e;
        Wf2pk[idx] = f2b(Wf2[row*64 + k]); return; }
    idx -= 4096;
    if (idx < 65536) {            // Wpw [128][512]
        int e = idx & 7, ln = (idx >> 3) & 63, ks = (idx >> 9) & 15, ot = idx >> 13;
        int row = ot*16 + (ln & 15), k = ks*32 + (ln >> 4)*8 + e;
        Wpwpk[idx] = f2b(Wpw[row*512 + k]); return; }
    idx -= 65536;
    if (idx < 256)   { int f = idx >> 2, j = idx & 3;
        W1p[idx] = (j < 3) ? Wf1[f*3 + j] : bf1[f]; return; }
    idx -= 256;
    if (idx < 8192)  { int m = idx >> 11, rem = idx & 2047;   // Wtb[m][c][k]
        int c = rem >> 4, k = rem & 15;
        Wtb[idx] = f2b(Wdw[(size_t)(c*4 + m)*16 + k]); return; }
    idx -= 8192;
    if (idx < 256)   { acc[idx] = 0.f; return; }              // accS|accS2
}

// ---------------- kA v3: X-chain, 32 pts/block, 512 thr, cvt_pk epilogues ----------------
#define SX 264
__global__ __launch_bounds__(512) void kA_mfma(
    const float* __restrict__ rep, const float* __restrict__ pts,
    const unsigned short* __restrict__ Wpk,
    const float* __restrict__ bxc, const float* __restrict__ bx1,
    const float* __restrict__ bx2, unsigned short* __restrict__ X3b)
{
    const unsigned short* Wxcpk = Wpk;
    const unsigned short* Wx1pk = Wpk + 16384;
    const unsigned short* Wx2pk = Wpk + 81920;
    __shared__ __align__(16) unsigned short X1s[32*SX];
    __shared__ __align__(16) unsigned short X2s[32*SX];
    const int tid = threadIdx.x;
    const int w = tid >> 6, lane = tid & 63, cl = lane & 15, lg = lane >> 4;
    const int mw = w & 1, nw = w >> 1;
    const int base = blockIdx.x * 32;
    const int q = base + mw*16 + cl;
    f32x4 z = {0.f,0.f,0.f,0.f};

    // ---- ph1 A-frag from global, packed conversions ----
    float r0 = rep[q*3+0], r1 = rep[q*3+1], r2 = rep[q*3+2];
    s16x8 aa[2];
    #pragma unroll
    for (int ks = 0; ks < 2; ++ks) {
        uint4 au;
        #pragma unroll
        for (int e2 = 0; e2 < 4; ++e2) {
            float v[2];
            #pragma unroll
            for (int h = 0; h < 2; ++h) {
                int j = ks*32 + lg*8 + e2*2 + h;
                float vv = 0.f;
                if (j < 48) {
                    int d = j >> 4, kk = j & 15;
                    float rv = (d == 0) ? r0 : ((d == 1) ? r1 : r2);
                    vv = pts[(size_t)(q*16 + kk)*3 + d] - rv;
                }
                v[h] = vv;
            }
            ((unsigned*)&au)[e2] = cvtpk(v[0], v[1]);
        }
        aa[ks] = __builtin_bit_cast(s16x8, au);
    }

    {   // ph1: X1 = relu(ptsl @ Wxc^T + b), K=64
        f32x4 acc[4] = {z,z,z,z};
        #pragma unroll
        for (int ks = 0; ks < 2; ++ks) {
            #pragma unroll
            for (int ct = 0; ct < 4; ++ct) {
                int ot = nw*4 + ct;
                s16x8 b = *(const s16x8*)&Wxcpk[((ot*2 + ks)*64 + lane)*8];
                acc[ct] = MFMA(aa[ks], b, acc[ct]);
            }
        }
        #pragma unroll
        for (int ct = 0; ct < 4; ++ct) {
            int o = nw*64 + ct*16 + cl;
            float bias = bxc[o];
            int rb = (mw*16 + lg*4)*SX + o;
            unsigned u0 = cvtpk(fmaxf(acc[ct][0]+bias,0.f), fmaxf(acc[ct][1]+bias,0.f));
            unsigned u1 = cvtpk(fmaxf(acc[ct][2]+bias,0.f), fmaxf(acc[ct][3]+bias,0.f));
            X1s[rb       ] = (unsigned short)u0;
            X1s[rb +   SX] = (unsigned short)(u0 >> 16);
            X1s[rb + 2*SX] = (unsigned short)u1;
            X1s[rb + 3*SX] = (unsigned short)(u1 >> 16);
        }
    }
    __syncthreads();

    {   // ph2: X2 = relu(X1 @ Wx1^T + b), K=256
        f32x4 acc[4] = {z,z,z,z};
        #pragma unroll
        for (int ks = 0; ks < 8; ++ks) {
            s16x8 a = *(const s16x8*)&X1s[(mw*16 + cl)*SX + ks*32 + lg*8];
            #pragma unroll
            for (int ct = 0; ct < 4; ++ct) {
                int ot = nw*4 + ct;
                s16x8 b = *(const s16x8*)&Wx1pk[((ot*8 + ks)*64 + lane)*8];
                acc[ct] = MFMA(a, b, acc[ct]);
            }
        }
        #pragma unroll
        for (int ct = 0; ct < 4; ++ct) {
            int o = nw*64 + ct*16 + cl;
            float bias = bx1[o];
            int rb = (mw*16 + lg*4)*SX + o;
            unsigned u0 = cvtpk(fmaxf(acc[ct][0]+bias,0.f), fmaxf(acc[ct][1]+bias,0.f));
            unsigned u1 = cvtpk(fmaxf(acc[ct][2]+bias,0.f), fmaxf(acc[ct][3]+bias,0.f));
            X2s[rb       ] = (unsigned short)u0;
            X2s[rb +   SX] = (unsigned short)(u0 >> 16);
            X2s[rb + 2*SX] = (unsigned short)u1;
            X2s[rb + 3*SX] = (unsigned short)(u1 >> 16);
        }
    }
    __syncthreads();

    {   // ph3: X3 = X2 @ Wx2^T + b (linear) -> global bf16 [p][256]
        f32x4 acc[4] = {z,z,z,z};
        #pragma unroll
        for (int ks = 0; ks < 8; ++ks) {
            s16x8 a = *(const s16x8*)&X2s[(mw*16 + cl)*SX + ks*32 + lg*8];
            #pragma unroll
            for (int ct = 0; ct < 4; ++ct) {
                int ot = nw*4 + ct;
                s16x8 b = *(const s16x8*)&Wx2pk[((ot*8 + ks)*64 + lane)*8];
                acc[ct] = MFMA(a, b, acc[ct]);
            }
        }
        #pragma unroll
        for (int ct = 0; ct < 4; ++ct) {
            int o = nw*64 + ct*16 + cl;
            float bias = bx2[o];
            size_t rb = (size_t)(base + mw*16 + lg*4)*256 + o;
            unsigned u0 = cvtpk(acc[ct][0]+bias, acc[ct][1]+bias);
            unsigned u1 = cvtpk(acc[ct][2]+bias, acc[ct][3]+bias);
            X3b[rb      ] = (unsigned short)u0;
            X3b[rb + 256] = (unsigned short)(u0 >> 16);
            X3b[rb + 512] = (unsigned short)u1;
            X3b[rb + 768] = (unsigned short)(u1 >> 16);
        }
    }
}

// ---------------- kB v7: barrier-free, cvt_pk, interleaved fts_X+depthwise ----------------
// 4 points/block (4096 blocks), 4 waves; wave w owns point p and LDS rows w*16..+15.
#define SF 72
__global__ __launch_bounds__(256) void kB_mfma(
    const float* __restrict__ rep, const float* __restrict__ pts,
    const float* __restrict__ fts, const float* __restrict__ W1p,
    const unsigned short* __restrict__ Wpk, const float* __restrict__ bf2,
    const unsigned short* __restrict__ Wtb, const float* __restrict__ bdw,
    const unsigned short* __restrict__ X3b, unsigned short* __restrict__ dwb)
{
    const unsigned short* Wf2pk = Wpk + 147456;
    __shared__ __align__(16) unsigned short fcT[128*SF];  // 18432 B
    const int tid = threadIdx.x;
    const int w = tid >> 6, lane = tid & 63, cl = lane & 15, lg = lane >> 4;
    const int p = blockIdx.x*4 + w;
    const int rw = w*16;

    // ---- issue global loads early ----
    const int frow = lane >> 2, fch = lane & 3;
    float4 fv[4];
    #pragma unroll
    for (int it = 0; it < 4; ++it)
        fv[it] = *(const float4*)&fts[((size_t)p*16 + frow)*64 + fch*4 + it*16];

    s16x8 xa = {0,0,0,0,0,0,0,0};
    if (lg < 2) xa = *(const s16x8*)&X3b[(size_t)p*256 + cl*16 + lg*8];

    const int row = p*16 + cl;
    float x0 = pts[(size_t)row*3+0] - rep[p*3+0];
    float x1 = pts[(size_t)row*3+1] - rep[p*3+1];
    float x2 = pts[(size_t)row*3+2] - rep[p*3+2];

    // ---- FC1 in regs (packed conversions) ----
    s16x8 hb[2];
    #pragma unroll
    for (int ks = 0; ks < 2; ++ks) {
        uint4 hu;
        #pragma unroll
        for (int e2 = 0; e2 < 4; ++e2) {
            int f0 = ks*32 + lg*8 + e2*2;
            float4 wa = *(const float4*)&W1p[f0*4];
            float4 wb = *(const float4*)&W1p[(f0+1)*4];
            float h0 = fmaxf(wa.w + wa.x*x0 + wa.y*x1 + wa.z*x2, 0.f);
            float h1 = fmaxf(wb.w + wb.x*x0 + wb.y*x1 + wb.z*x2, 0.f);
            ((unsigned*)&hu)[e2] = cvtpk(h0, h1);
        }
        hb[ks] = __builtin_bit_cast(s16x8, hu);
    }

    // ---- stage fts transposed (packed conversions, scalar scattered writes) ----
    #pragma unroll
    for (int it = 0; it < 4; ++it) {
        int c0 = fch*4 + it*16;
        unsigned u0 = cvtpk(fv[it].x, fv[it].y);
        unsigned u1 = cvtpk(fv[it].z, fv[it].w);
        int rb = (64 + c0)*SF + rw + frow;
        fcT[rb       ] = (unsigned short)u0;
        fcT[rb +   SF] = (unsigned short)(u0 >> 16);
        fcT[rb + 2*SF] = (unsigned short)u1;
        fcT[rb + 3*SF] = (unsigned short)(u1 >> 16);
    }

    f32x4 z = {0.f,0.f,0.f,0.f};
    // ---- FC2 swapped MFMA: D[g][row_local] ----
    {
        f32x4 acc2[4] = {z,z,z,z};
        #pragma unroll
        for (int ks = 0; ks < 2; ++ks) {
            #pragma unroll
            for (int gt = 0; gt < 4; ++gt) {
                s16x8 a = *(const s16x8*)&Wf2pk[((gt*2 + ks)*64 + lane)*8];
                acc2[gt] = MFMA(a, hb[ks], acc2[gt]);
            }
        }
        #pragma unroll
        for (int gt = 0; gt < 4; ++gt) {
            int g0 = gt*16 + lg*4;
            unsigned u0 = cvtpk(fmaxf(acc2[gt][0]+bf2[g0+0],0.f),
                                fmaxf(acc2[gt][1]+bf2[g0+1],0.f));
            unsigned u1 = cvtpk(fmaxf(acc2[gt][2]+bf2[g0+2],0.f),
                                fmaxf(acc2[gt][3]+bf2[g0+3],0.f));
            int rb = g0*SF + rw + cl;
            fcT[rb       ] = (unsigned short)u0;
            fcT[rb +   SF] = (unsigned short)(u0 >> 16);
            fcT[rb + 2*SF] = (unsigned short)u1;
            fcT[rb + 3*SF] = (unsigned short)(u1 >> 16);
        }
    }

    // ---- interleaved fts_X + depthwise per ct (fx lives briefly) ----
    #pragma unroll
    for (int ct = 0; ct < 8; ++ct) {
        int c = ct*16 + cl;
        s16x8 b = *(const s16x8*)&fcT[c*SF + rw + (lg & 1)*8];
        f32x4 fx = MFMA(xa, b, z);

        float4 b4 = *(const float4*)&bdw[c*4];
        float om[4];
        #pragma unroll
        for (int m = 0; m < 4; ++m) {
            ushort4 wu = *(const ushort4*)&Wtb[m*2048 + c*16 + lg*4];
            float s = fx[0]*b2f(wu.x) + fx[1]*b2f(wu.y)
                    + fx[2]*b2f(wu.z) + fx[3]*b2f(wu.w);
            s += __shfl_xor(s, 16);
            s += __shfl_xor(s, 32);
            om[m] = s + ((const float*)&b4)[m];
        }
        if (lg == 0) {
            unsigned u0 = cvtpk(om[0], om[1]);
            unsigned u1 = cvtpk(om[2], om[3]);
            uint2 pk; pk.x = u0; pk.y = u1;
            *(uint2*)&dwb[(size_t)p*512 + c*4] = pk;
        }
    }
}

// ---------------- kC: pointwise MFMA GEMM + fused BN partial stats ----------------
__global__ __launch_bounds__(256) void kC_mfma(
    const unsigned short* __restrict__ dwb, const unsigned short* __restrict__ Wpk,
    const float* __restrict__ bpw, float* __restrict__ y,
    float* __restrict__ accS, float* __restrict__ accS2)
{
    const unsigned short* Wpwpk = Wpk + 151552;
    const int tid = threadIdx.x;
    const int w = tid >> 6, lane = tid & 63, cl = lane & 15, lg = lane >> 4;
    const int m0 = blockIdx.x*32 + (w & 1)*16;
    const int nh = w >> 1;
    f32x4 z = {0.f,0.f,0.f,0.f};
    f32x4 acc[4] = {z,z,z,z};
    for (int ks = 0; ks < 16; ++ks) {
        s16x8 a = *(const s16x8*)&dwb[(size_t)(m0 + cl)*512 + ks*32 + lg*8];
        #pragma unroll
        for (int ct = 0; ct < 4; ++ct) {
            int ot = nh*4 + ct;
            s16x8 b = *(const s16x8*)&Wpwpk[((ot*16 + ks)*64 + lane)*8];
            acc[ct] = MFMA(a, b, acc[ct]);
        }
    }
    #pragma unroll
    for (int ct = 0; ct < 4; ++ct) {
        int o = nh*64 + ct*16 + cl;
        float bias = bpw[o];
        float s1 = 0.f, s2 = 0.f;
        #pragma unroll
        for (int r = 0; r < 4; ++r) {
            float v = acc[ct][r] + bias;
            y[(size_t)(m0 + lg*4 + r)*128 + o] = v;
            s1 += v; s2 += v*v;
        }
        s1 += __shfl_xor(s1, 16); s2 += __shfl_xor(s2, 16);
        s1 += __shfl_xor(s1, 32); s2 += __shfl_xor(s2, 32);
        if (lg == 0) {
            atomicAdd(accS + o, s1);
            atomicAdd(accS2 + o, s2);
        }
    }
}

// ---------------- kE: BN finalize (inline) + normalize + relu ----------------
__global__ __launch_bounds__(256) void kE_final(
    const float* __restrict__ y, const float* __restrict__ accS,
    const float* __restrict__ accS2, const float* __restrict__ gamma,
    const float* __restrict__ beta, float* __restrict__ out)
{
    __shared__ float stl[256];
    const int tid = threadIdx.x;
    if (tid < 128) {
        float mean = accS[tid] * (1.f/NPTS);
        float var  = accS2[tid] * (1.f/NPTS) - mean*mean;
        float rstd = rsqrtf(var + 1e-5f);
        float sc = gamma[tid] * rstd;
        stl[tid] = sc;
        stl[128 + tid] = beta[tid] - mean*sc;
    }
    __syncthreads();
    const int idx = blockIdx.x*256 + tid;
    float4 v = ((const float4*)y)[idx];
    int o0 = (idx & 31) << 2;
    float4 sc = *(const float4*)&stl[o0];
    float4 sh = *(const float4*)&stl[128 + o0];
    float4 r;
    r.x = fmaxf(v.x*sc.x + sh.x, 0.f);
    r.y = fmaxf(v.y*sc.y + sh.y, 0.f);
    r.z = fmaxf(v.z*sc.z + sh.z, 0.f);
    r.w = fmaxf(v.w*sc.w + sh.w, 0.f);
    ((float4*)out)[idx] = r;
}

extern "C" void kernel_launch(void* const* d_in, const int* in_sizes, int n_in,
                              void* d_out, int out_size, void* d_ws, size_t ws_size,
                              hipStream_t stream) {
    const float* rep  = (const float*)d_in[0];
    const float* pts  = (const float*)d_in[1];
    const float* fts  = (const float*)d_in[2];
    const float* Wf1  = (const float*)d_in[3];
    const float* bf1  = (const float*)d_in[4];
    const float* Wf2  = (const float*)d_in[5];
    const float* bf2  = (const float*)d_in[6];
    const float* Wxc  = (const float*)d_in[7];
    const float* bxc  = (const float*)d_in[8];
    const float* Wx1  = (const float*)d_in[9];
    const float* bx1  = (const float*)d_in[10];
    const float* Wx2  = (const float*)d_in[11];
    const float* bx2  = (const float*)d_in[12];
    const float* Wdw  = (const float*)d_in[13];
    const float* bdw  = (const float*)d_in[14];
    const float* Wpw  = (const float*)d_in[15];
    const float* bpw  = (const float*)d_in[16];
    const float* gam  = (const float*)d_in[17];
    const float* bet  = (const float*)d_in[18];

    unsigned short* X3b = (unsigned short*)d_ws;                 // 16384*256 bf16
    unsigned short* dwb = X3b + (size_t)NPTS*256;                // 16384*512 bf16
    float* y   = (float*)(dwb + (size_t)NPTS*512);               // 16384*128 f32
    float* acc = y + (size_t)NPTS*128;                           // 256 (accS|accS2)
    unsigned short* Wpk = (unsigned short*)(acc + 256);          // 217088 bf16
    float* W1p = (float*)(Wpk + 217088);                         // 256 f32
    unsigned short* Wtb = (unsigned short*)(W1p + 256);          // 8192 bf16

    kW_cvt<<<882, 256, 0, stream>>>(Wxc, Wx1, Wx2, Wf2, Wpw, Wf1, bf1, Wdw,
                                    Wpk, W1p, Wtb, acc);
    kA_mfma<<<NPTS/32, 512, 0, stream>>>(rep, pts, Wpk, bxc, bx1, bx2, X3b);
    kB_mfma<<<NPTS/4, 256, 0, stream>>>(rep, pts, fts, W1p, Wpk, bf2, Wtb, bdw, X3b, dwb);
    kC_mfma<<<NPTS/32, 256, 0, stream>>>(dwb, Wpk, bpw, y, acc, acc + 128);
    kE_final<<<(NPTS*128/4)/256, 256, 0, stream>>>(y, acc, acc + 128, gam, bet, (float*)d_out);
}

// Round 11
// 115.611 us; speedup vs baseline: 1.4560x; 1.0105x over previous
//
#include <hip/hip_runtime.h>

// XConv bf16-MFMA pipeline, fragment-packed weights + packed dw handoff.
// N=16, P=1024, K=16, D=3, Cf=64, Fin=64, Ccat=128, DM=4, Cout=128.
//
// MFMA conventions (mfma_f32_16x16x32_bf16, m89-verified):
//  A-frag: lane&15 = M-row, k = (lane>>4)*8 + [0..7]  ([M][K] row-major)
//  B-frag: lane&15 = N-col, k = (lane>>4)*8 + [0..7]  ([N][K] row-major)
//  D:      col(N) = lane&15, row(M) = (lane>>4)*4 + reg
//
// Packed weight layout (per [O][K] weight, 16-col tiles, K-steps of 32):
//  Wpk[((ot*(K/32) + ks)*64 + lane)*8 + e] = W[ot*16 + (lane&15)][ks*32 + (lane>>4)*8 + e]
// Packed dw handoff (A-frag order for kC):
//  dwPk[(((p>>4)*16 + (k>>5))*64 + ((k>>3)&3)*16 + (p&15))*8 + (k&7)] = dw[p][k]

#define NPTS 16384

typedef short  s16x8 __attribute__((ext_vector_type(8)));
typedef float  f32x4 __attribute__((ext_vector_type(4)));

__device__ inline unsigned short f2b(float f) {
    unsigned u = __builtin_bit_cast(unsigned, f);
    unsigned r = u + 0x7FFF + ((u >> 16) & 1);
    return (unsigned short)(r >> 16);
}
__device__ inline float b2f(unsigned short b) {
    return __builtin_bit_cast(float, (unsigned)b << 16);
}
// packed RNE f32x2 -> bf16x2 (lo -> [15:0], hi -> [31:16])
__device__ inline unsigned cvtpk(float lo, float hi) {
    unsigned r;
    asm("v_cvt_pk_bf16_f32 %0, %1, %2" : "=v"(r) : "v"(lo), "v"(hi));
    return r;
}

#define MFMA(a,b,c) __builtin_amdgcn_mfma_f32_16x16x32_bf16((a),(b),(c),0,0,0)

// ---------------- kW: weight prep (frag-packed) + W1 pack + Wt + acc zero ----------------
__global__ __launch_bounds__(256) void kW_cvt(
    const float* __restrict__ Wxc, const float* __restrict__ Wx1,
    const float* __restrict__ Wx2, const float* __restrict__ Wf2,
    const float* __restrict__ Wpw, const float* __restrict__ Wf1,
    const float* __restrict__ bf1, const float* __restrict__ Wdw,
    unsigned short* __restrict__ Wpk, float* __restrict__ W1p,
    unsigned short* __restrict__ Wtb, float* __restrict__ acc)
{
    unsigned short* Wxcpk = Wpk;             // O=256 K=64   : 16384
    unsigned short* Wx1pk = Wpk + 16384;     // O=256 K=256  : 65536
    unsigned short* Wx2pk = Wpk + 81920;     // O=256 K=256  : 65536
    unsigned short* Wf2pk = Wpk + 147456;    // O=64  K=64   : 4096
    unsigned short* Wpwpk = Wpk + 151552;    // O=128 K=512  : 65536
    int idx = blockIdx.x * 256 + threadIdx.x;
    if (idx < 16384) {            // Wxc [256][48] -> K=64 pad
        int e = idx & 7, ln = (idx >> 3) & 63, ks = (idx >> 9) & 1, ot = idx >> 10;
        int row = ot*16 + (ln & 15), k = ks*32 + (ln >> 4)*8 + e;
        Wxcpk[idx] = (k < 48) ? f2b(Wxc[row*48 + k]) : 0; return; }
    idx -= 16384;
    if (idx < 65536) {            // Wx1 [256][256]
        int e = idx & 7, ln = (idx >> 3) & 63, ks = (idx >> 9) & 7, ot = idx >> 12;
        int row = ot*16 + (ln & 15), k = ks*32 + (ln >> 4)*8 + e;
        Wx1pk[idx] = f2b(Wx1[row*256 + k]); return; }
    idx -= 65536;
    if (idx < 65536) {            // Wx2 [256][256]
        int e = idx & 7, ln = (idx >> 3) & 63, ks = (idx >> 9) & 7, ot = idx >> 12;
        int row = ot*16 + (ln & 15), k = ks*32 + (ln >> 4)*8 + e;
        Wx2pk[idx] = f2b(Wx2[row*256 + k]); return; }
    idx -= 65536;
    if (idx < 4096) {             // Wf2 [64][64]
        int e = idx & 7, ln = (idx >> 3) & 63, ks = (idx >> 9) & 1, ot = idx >> 10;
        int row = ot*16 + (ln & 15), k = ks*32 + (ln >> 4)*8 + e;
        Wf2pk[idx] = f2b(Wf2[row*64 + k]); return; }
    idx -= 4096;
    if (idx < 65536) {            // Wpw [128][512]
        int e = idx & 7, ln = (idx >> 3) & 63, ks = (idx >> 9) & 15, ot = idx >> 13;
        int row = ot*16 + (ln & 15), k = ks*32 + (ln >> 4)*8 + e;
        Wpwpk[idx] = f2b(Wpw[row*512 + k]); return; }
    idx -= 65536;
    if (idx < 256)   { int f = idx >> 2, j = idx & 3;
        W1p[idx] = (j < 3) ? Wf1[f*3 + j] : bf1[f]; return; }
    idx -= 256;
    if (idx < 8192)  { int m = idx >> 11, rem = idx & 2047;   // Wtb[m][c][k]
        int c = rem >> 4, k = rem & 15;
        Wtb[idx] = f2b(Wdw[(size_t)(c*4 + m)*16 + k]); return; }
    idx -= 8192;
    if (idx < 256)   { acc[idx] = 0.f; return; }              // accS|accS2
}

// ---------------- kA v3: X-chain, 32 pts/block, 512 thr, cvt_pk epilogues ----------------
#define SX 264
__global__ __launch_bounds__(512) void kA_mfma(
    const float* __restrict__ rep, const float* __restrict__ pts,
    const unsigned short* __restrict__ Wpk,
    const float* __restrict__ bxc, const float* __restrict__ bx1,
    const float* __restrict__ bx2, unsigned short* __restrict__ X3b)
{
    const unsigned short* Wxcpk = Wpk;
    const unsigned short* Wx1pk = Wpk + 16384;
    const unsigned short* Wx2pk = Wpk + 81920;
    __shared__ __align__(16) unsigned short X1s[32*SX];
    __shared__ __align__(16) unsigned short X2s[32*SX];
    const int tid = threadIdx.x;
    const int w = tid >> 6, lane = tid & 63, cl = lane & 15, lg = lane >> 4;
    const int mw = w & 1, nw = w >> 1;
    const int base = blockIdx.x * 32;
    const int q = base + mw*16 + cl;
    f32x4 z = {0.f,0.f,0.f,0.f};

    // ---- ph1 A-frag from global, packed conversions ----
    float r0 = rep[q*3+0], r1 = rep[q*3+1], r2 = rep[q*3+2];
    s16x8 aa[2];
    #pragma unroll
    for (int ks = 0; ks < 2; ++ks) {
        uint4 au;
        #pragma unroll
        for (int e2 = 0; e2 < 4; ++e2) {
            float v[2];
            #pragma unroll
            for (int h = 0; h < 2; ++h) {
                int j = ks*32 + lg*8 + e2*2 + h;
                float vv = 0.f;
                if (j < 48) {
                    int d = j >> 4, kk = j & 15;
                    float rv = (d == 0) ? r0 : ((d == 1) ? r1 : r2);
                    vv = pts[(size_t)(q*16 + kk)*3 + d] - rv;
                }
                v[h] = vv;
            }
            ((unsigned*)&au)[e2] = cvtpk(v[0], v[1]);
        }
        aa[ks] = __builtin_bit_cast(s16x8, au);
    }

    {   // ph1: X1 = relu(ptsl @ Wxc^T + b), K=64
        f32x4 acc[4] = {z,z,z,z};
        #pragma unroll
        for (int ks = 0; ks < 2; ++ks) {
            #pragma unroll
            for (int ct = 0; ct < 4; ++ct) {
                int ot = nw*4 + ct;
                s16x8 b = *(const s16x8*)&Wxcpk[((ot*2 + ks)*64 + lane)*8];
                acc[ct] = MFMA(aa[ks], b, acc[ct]);
            }
        }
        #pragma unroll
        for (int ct = 0; ct < 4; ++ct) {
            int o = nw*64 + ct*16 + cl;
            float bias = bxc[o];
            int rb = (mw*16 + lg*4)*SX + o;
            unsigned u0 = cvtpk(fmaxf(acc[ct][0]+bias,0.f), fmaxf(acc[ct][1]+bias,0.f));
            unsigned u1 = cvtpk(fmaxf(acc[ct][2]+bias,0.f), fmaxf(acc[ct][3]+bias,0.f));
            X1s[rb       ] = (unsigned short)u0;
            X1s[rb +   SX] = (unsigned short)(u0 >> 16);
            X1s[rb + 2*SX] = (unsigned short)u1;
            X1s[rb + 3*SX] = (unsigned short)(u1 >> 16);
        }
    }
    __syncthreads();

    {   // ph2: X2 = relu(X1 @ Wx1^T + b), K=256
        f32x4 acc[4] = {z,z,z,z};
        #pragma unroll
        for (int ks = 0; ks < 8; ++ks) {
            s16x8 a = *(const s16x8*)&X1s[(mw*16 + cl)*SX + ks*32 + lg*8];
            #pragma unroll
            for (int ct = 0; ct < 4; ++ct) {
                int ot = nw*4 + ct;
                s16x8 b = *(const s16x8*)&Wx1pk[((ot*8 + ks)*64 + lane)*8];
                acc[ct] = MFMA(a, b, acc[ct]);
            }
        }
        #pragma unroll
        for (int ct = 0; ct < 4; ++ct) {
            int o = nw*64 + ct*16 + cl;
            float bias = bx1[o];
            int rb = (mw*16 + lg*4)*SX + o;
            unsigned u0 = cvtpk(fmaxf(acc[ct][0]+bias,0.f), fmaxf(acc[ct][1]+bias,0.f));
            unsigned u1 = cvtpk(fmaxf(acc[ct][2]+bias,0.f), fmaxf(acc[ct][3]+bias,0.f));
            X2s[rb       ] = (unsigned short)u0;
            X2s[rb +   SX] = (unsigned short)(u0 >> 16);
            X2s[rb + 2*SX] = (unsigned short)u1;
            X2s[rb + 3*SX] = (unsigned short)(u1 >> 16);
        }
    }
    __syncthreads();

    {   // ph3: X3 = X2 @ Wx2^T + b (linear) -> global bf16 [p][256]
        f32x4 acc[4] = {z,z,z,z};
        #pragma unroll
        for (int ks = 0; ks < 8; ++ks) {
            s16x8 a = *(const s16x8*)&X2s[(mw*16 + cl)*SX + ks*32 + lg*8];
            #pragma unroll
            for (int ct = 0; ct < 4; ++ct) {
                int ot = nw*4 + ct;
                s16x8 b = *(const s16x8*)&Wx2pk[((ot*8 + ks)*64 + lane)*8];
                acc[ct] = MFMA(a, b, acc[ct]);
            }
        }
        #pragma unroll
        for (int ct = 0; ct < 4; ++ct) {
            int o = nw*64 + ct*16 + cl;
            float bias = bx2[o];
            size_t rb = (size_t)(base + mw*16 + lg*4)*256 + o;
            unsigned u0 = cvtpk(acc[ct][0]+bias, acc[ct][1]+bias);
            unsigned u1 = cvtpk(acc[ct][2]+bias, acc[ct][3]+bias);
            X3b[rb      ] = (unsigned short)u0;
            X3b[rb + 256] = (unsigned short)(u0 >> 16);
            X3b[rb + 512] = (unsigned short)u1;
            X3b[rb + 768] = (unsigned short)(u1 >> 16);
        }
    }
}

// ---------------- kB v8: barrier-free + packed dw output ----------------
// 4 points/block (4096 blocks), 4 waves; wave w owns point p and LDS rows w*16..+15.
#define SF 72
__global__ __launch_bounds__(256) void kB_mfma(
    const float* __restrict__ rep, const float* __restrict__ pts,
    const float* __restrict__ fts, const float* __restrict__ W1p,
    const unsigned short* __restrict__ Wpk, const float* __restrict__ bf2,
    const unsigned short* __restrict__ Wtb, const float* __restrict__ bdw,
    const unsigned short* __restrict__ X3b, unsigned short* __restrict__ dwPk)
{
    const unsigned short* Wf2pk = Wpk + 147456;
    __shared__ __align__(16) unsigned short fcT[128*SF];  // 18432 B
    const int tid = threadIdx.x;
    const int w = tid >> 6, lane = tid & 63, cl = lane & 15, lg = lane >> 4;
    const int p = blockIdx.x*4 + w;
    const int rw = w*16;

    // ---- issue global loads early ----
    const int frow = lane >> 2, fch = lane & 3;
    float4 fv[4];
    #pragma unroll
    for (int it = 0; it < 4; ++it)
        fv[it] = *(const float4*)&fts[((size_t)p*16 + frow)*64 + fch*4 + it*16];

    s16x8 xa = {0,0,0,0,0,0,0,0};
    if (lg < 2) xa = *(const s16x8*)&X3b[(size_t)p*256 + cl*16 + lg*8];

    const int row = p*16 + cl;
    float x0 = pts[(size_t)row*3+0] - rep[p*3+0];
    float x1 = pts[(size_t)row*3+1] - rep[p*3+1];
    float x2 = pts[(size_t)row*3+2] - rep[p*3+2];

    // ---- FC1 in regs (packed conversions) ----
    s16x8 hb[2];
    #pragma unroll
    for (int ks = 0; ks < 2; ++ks) {
        uint4 hu;
        #pragma unroll
        for (int e2 = 0; e2 < 4; ++e2) {
            int f0 = ks*32 + lg*8 + e2*2;
            float4 wa = *(const float4*)&W1p[f0*4];
            float4 wb = *(const float4*)&W1p[(f0+1)*4];
            float h0 = fmaxf(wa.w + wa.x*x0 + wa.y*x1 + wa.z*x2, 0.f);
            float h1 = fmaxf(wb.w + wb.x*x0 + wb.y*x1 + wb.z*x2, 0.f);
            ((unsigned*)&hu)[e2] = cvtpk(h0, h1);
        }
        hb[ks] = __builtin_bit_cast(s16x8, hu);
    }

    // ---- stage fts transposed (packed conversions, scalar scattered writes) ----
    #pragma unroll
    for (int it = 0; it < 4; ++it) {
        int c0 = fch*4 + it*16;
        unsigned u0 = cvtpk(fv[it].x, fv[it].y);
        unsigned u1 = cvtpk(fv[it].z, fv[it].w);
        int rb = (64 + c0)*SF + rw + frow;
        fcT[rb       ] = (unsigned short)u0;
        fcT[rb +   SF] = (unsigned short)(u0 >> 16);
        fcT[rb + 2*SF] = (unsigned short)u1;
        fcT[rb + 3*SF] = (unsigned short)(u1 >> 16);
    }

    f32x4 z = {0.f,0.f,0.f,0.f};
    // ---- FC2 swapped MFMA: D[g][row_local] ----
    {
        f32x4 acc2[4] = {z,z,z,z};
        #pragma unroll
        for (int ks = 0; ks < 2; ++ks) {
            #pragma unroll
            for (int gt = 0; gt < 4; ++gt) {
                s16x8 a = *(const s16x8*)&Wf2pk[((gt*2 + ks)*64 + lane)*8];
                acc2[gt] = MFMA(a, hb[ks], acc2[gt]);
            }
        }
        #pragma unroll
        for (int gt = 0; gt < 4; ++gt) {
            int g0 = gt*16 + lg*4;
            unsigned u0 = cvtpk(fmaxf(acc2[gt][0]+bf2[g0+0],0.f),
                                fmaxf(acc2[gt][1]+bf2[g0+1],0.f));
            unsigned u1 = cvtpk(fmaxf(acc2[gt][2]+bf2[g0+2],0.f),
                                fmaxf(acc2[gt][3]+bf2[g0+3],0.f));
            int rb = g0*SF + rw + cl;
            fcT[rb       ] = (unsigned short)u0;
            fcT[rb +   SF] = (unsigned short)(u0 >> 16);
            fcT[rb + 2*SF] = (unsigned short)u1;
            fcT[rb + 3*SF] = (unsigned short)(u1 >> 16);
        }
    }

    // ---- interleaved fts_X + depthwise per ct; packed dw writes ----
    #pragma unroll
    for (int ct = 0; ct < 8; ++ct) {
        int c = ct*16 + cl;
        s16x8 b = *(const s16x8*)&fcT[c*SF + rw + (lg & 1)*8];
        f32x4 fx = MFMA(xa, b, z);

        float4 b4 = *(const float4*)&bdw[c*4];
        float om[4];
        #pragma unroll
        for (int m = 0; m < 4; ++m) {
            ushort4 wu = *(const ushort4*)&Wtb[m*2048 + c*16 + lg*4];
            float s = fx[0]*b2f(wu.x) + fx[1]*b2f(wu.y)
                    + fx[2]*b2f(wu.z) + fx[3]*b2f(wu.w);
            s += __shfl_xor(s, 16);
            s += __shfl_xor(s, 32);
            om[m] = s + ((const float*)&b4)[m];
        }
        if (lg == 0) {
            // k0 = c*4 = ct*64 + cl*4; packed A-frag address for kC
            unsigned u0 = cvtpk(om[0], om[1]);
            unsigned u1 = cvtpk(om[2], om[3]);
            uint2 pk; pk.x = u0; pk.y = u1;
            size_t a = ((((size_t)(p >> 4)*16 + ct*2 + (cl >> 3))*64
                        + ((cl >> 1) & 3)*16 + (p & 15))*8 + (cl & 1)*4);
            *(uint2*)&dwPk[a] = pk;
        }
    }
}

// ---------------- kC: pointwise MFMA GEMM (packed A) + BN stats, y bf16 ----------------
__global__ __launch_bounds__(256) void kC_mfma(
    const unsigned short* __restrict__ dwPk, const unsigned short* __restrict__ Wpk,
    const float* __restrict__ bpw, unsigned short* __restrict__ yb,
    float* __restrict__ accS, float* __restrict__ accS2)
{
    const unsigned short* Wpwpk = Wpk + 151552;
    const int tid = threadIdx.x;
    const int w = tid >> 6, lane = tid & 63, cl = lane & 15, lg = lane >> 4;
    const int mt = blockIdx.x*2 + (w & 1);     // 16-point m-tile
    const int m0 = mt*16;
    const int nh = w >> 1;
    f32x4 z = {0.f,0.f,0.f,0.f};
    f32x4 acc[4] = {z,z,z,z};
    for (int ks = 0; ks < 16; ++ks) {
        s16x8 a = *(const s16x8*)&dwPk[(((size_t)mt*16 + ks)*64 + lane)*8];
        #pragma unroll
        for (int ct = 0; ct < 4; ++ct) {
            int ot = nh*4 + ct;
            s16x8 b = *(const s16x8*)&Wpwpk[((ot*16 + ks)*64 + lane)*8];
            acc[ct] = MFMA(a, b, acc[ct]);
        }
    }
    #pragma unroll
    for (int ct = 0; ct < 4; ++ct) {
        int o = nh*64 + ct*16 + cl;
        float bias = bpw[o];
        float s1 = 0.f, s2 = 0.f;
        #pragma unroll
        for (int r = 0; r < 4; ++r) {
            float v = acc[ct][r] + bias;
            yb[(size_t)(m0 + lg*4 + r)*128 + o] = f2b(v);
            s1 += v; s2 += v*v;
        }
        s1 += __shfl_xor(s1, 16); s2 += __shfl_xor(s2, 16);
        s1 += __shfl_xor(s1, 32); s2 += __shfl_xor(s2, 32);
        if (lg == 0) {
            atomicAdd(accS + o, s1);
            atomicAdd(accS2 + o, s2);
        }
    }
}

// ---------------- kE: BN finalize (inline) + normalize + relu, bf16 y in ----------------
__global__ __launch_bounds__(256) void kE_final(
    const unsigned short* __restrict__ yb, const float* __restrict__ accS,
    const float* __restrict__ accS2, const float* __restrict__ gamma,
    const float* __restrict__ beta, float* __restrict__ out)
{
    __shared__ float stl[256];
    const int tid = threadIdx.x;
    if (tid < 128) {
        float mean = accS[tid] * (1.f/NPTS);
        float var  = accS2[tid] * (1.f/NPTS) - mean*mean;
        float rstd = rsqrtf(var + 1e-5f);
        float sc = gamma[tid] * rstd;
        stl[tid] = sc;
        stl[128 + tid] = beta[tid] - mean*sc;
    }
    __syncthreads();
    const int idx = blockIdx.x*256 + tid;
    ushort4 u = *(const ushort4*)&yb[(size_t)idx*4];
    int o0 = (idx & 31) << 2;
    float4 sc = *(const float4*)&stl[o0];
    float4 sh = *(const float4*)&stl[128 + o0];
    float4 r;
    r.x = fmaxf(b2f(u.x)*sc.x + sh.x, 0.f);
    r.y = fmaxf(b2f(u.y)*sc.y + sh.y, 0.f);
    r.z = fmaxf(b2f(u.z)*sc.z + sh.z, 0.f);
    r.w = fmaxf(b2f(u.w)*sc.w + sh.w, 0.f);
    ((float4*)out)[idx] = r;
}

extern "C" void kernel_launch(void* const* d_in, const int* in_sizes, int n_in,
                              void* d_out, int out_size, void* d_ws, size_t ws_size,
                              hipStream_t stream) {
    const float* rep  = (const float*)d_in[0];
    const float* pts  = (const float*)d_in[1];
    const float* fts  = (const float*)d_in[2];
    const float* Wf1  = (const float*)d_in[3];
    const float* bf1  = (const float*)d_in[4];
    const float* Wf2  = (const float*)d_in[5];
    const float* bf2  = (const float*)d_in[6];
    const float* Wxc  = (const float*)d_in[7];
    const float* bxc  = (const float*)d_in[8];
    const float* Wx1  = (const float*)d_in[9];
    const float* bx1  = (const float*)d_in[10];
    const float* Wx2  = (const float*)d_in[11];
    const float* bx2  = (const float*)d_in[12];
    const float* Wdw  = (const float*)d_in[13];
    const float* bdw  = (const float*)d_in[14];
    const float* Wpw  = (const float*)d_in[15];
    const float* bpw  = (const float*)d_in[16];
    const float* gam  = (const float*)d_in[17];
    const float* bet  = (const float*)d_in[18];

    unsigned short* X3b  = (unsigned short*)d_ws;                // 16384*256 bf16
    unsigned short* dwPk = X3b + (size_t)NPTS*256;               // 16384*512 bf16
    unsigned short* yb   = dwPk + (size_t)NPTS*512;              // 16384*128 bf16
    float* acc = (float*)(yb + (size_t)NPTS*128);                // 256 (accS|accS2)
    unsigned short* Wpk = (unsigned short*)(acc + 256);          // 217088 bf16
    float* W1p = (float*)(Wpk + 217088);                         // 256 f32
    unsigned short* Wtb = (unsigned short*)(W1p + 256);          // 8192 bf16

    kW_cvt<<<882, 256, 0, stream>>>(Wxc, Wx1, Wx2, Wf2, Wpw, Wf1, bf1, Wdw,
                                    Wpk, W1p, Wtb, acc);
    kA_mfma<<<NPTS/32, 512, 0, stream>>>(rep, pts, Wpk, bxc, bx1, bx2, X3b);
    kB_mfma<<<NPTS/4, 256, 0, stream>>>(rep, pts, fts, W1p, Wpk, bf2, Wtb, bdw, X3b, dwPk);
    kC_mfma<<<NPTS/32, 256, 0, stream>>>(dwPk, Wpk, bpw, yb, acc, acc + 128);
    kE_final<<<(NPTS*128/4)/256, 256, 0, stream>>>(yb, acc, acc + 128, gam, bet, (float*)d_out);
}